// Round 10
// baseline (166.194 us; speedup 1.0000x reference)
//
#include <hip/hip_runtime.h>
#include <math.h>

#define NPAIRS  262144
#define D4      32                  // 128 floats = 32 float4 per row
#define TPB     256
#define NBLK    2048
#define GPB     (TPB / 32)          // 8 groups per block
#define NGROUPS (NBLK * GPB)        // 16384
#define PPG     (NPAIRS / NGROUPS)  // 16 pairs per group per list

// 32-lane group per pair; lane l holds float4 #l of each row (512B coalesced).
//
// History: R1 shfl-diet, R2 +occupancy, R4 MLP-batching all null -> pair
// kernel sits at an L1 miss-path (MSHR) floor (~26 GB/s/CU effective, 17% of
// L1 bw; extra waves can't add outstanding-line capacity). R5-R9 closed-form
// pos: abandoned after 5 losses -- and the model says pos was the SMALL term:
// pos b-rows are the class row set enumerated repeatedly (L1 hits), so ~80%
// of line fills are neg's random rows.
//
// R10, on the R2 base:
//  1) neg loads use __builtin_nontemporal_load (nt): neg rows have ~zero
//     within-CU reuse, so L1-allocating them is pure MSHR pressure. If nt
//     skips L1 allocation, neg streams at L2 rate.
//  2) pos a-row i0-cache, SPILL-FREE form: i0/a0 fixed before the loop,
//     per-iter ternary, no loop-carried conditional mutation (unlike R8's
//     scratch disaster). Pos pairs share i in runs of ~63.
//
// Reduction: per-block partials to d_ws + finalize kernel. Prev-session
// lesson: 2048-block atomicAdd to the SAME two addresses serializes at the
// TCC (~25us tail) -- never again.

typedef float f4 __attribute__((ext_vector_type(4)));

__global__ __launch_bounds__(TPB, 6) void pair_kernel(
    const float* __restrict__ X,
    const int2*  __restrict__ pos_p,   // pos_idx as int2 stream
    const int2*  __restrict__ neg_p,   // neg_idx as int2 stream
    const float* __restrict__ h_bias,
    float* __restrict__ partials)
{
    const int lane  = threadIdx.x & 31;
    const int group = threadIdx.x >> 5;
    const int gid   = (blockIdx.x * TPB + threadIdx.x) >> 5;

    const float4* __restrict__ X4 = (const float4*)X;
    const f4*     __restrict__ Xv = (const f4*)X;

    // numerically stable softplus(h_bias)
    const float hb   = h_bias[0];
    const float bias = fmaxf(hb, 0.0f) + log1pf(expf(-fabsf(hb)));

    // Preload this group's 16 pairs from each list (lanes 16..31 duplicate
    // lanes 0..15 -- same cacheline; shfl broadcasts read lanes 0..15).
    const int2 pp = pos_p[gid * PPG + (lane & (PPG - 1))];
    const int2 np = neg_p[gid * PPG + (lane & (PPG - 1))];

    // ---------------- positive pairs: i0 register cache --------------------
    // i is group-uniform; consecutive pairs share i in runs (~63), so pair 0's
    // a-row serves ~90% of iterations. a0/i0 are loop-invariant (read-only in
    // the loop) -> no conditional loop-carried state, no scratch.
    const int i0 = __shfl(pp.x, 0, 32);
    const float4 a0 = X4[i0 * D4 + lane];

    float posAcc = 0.0f;
    #pragma unroll
    for (int t = 0; t < PPG; ++t) {
        const int i = __shfl(pp.x, t, 32);
        const int j = __shfl(pp.y, t, 32);
        float4 a;
        if (i == i0) a = a0;
        else         a = X4[i * D4 + lane];
        const float4 b = X4[j * D4 + lane];
        float d;
        d = a.x - b.x; posAcc = fmaf(d, d, posAcc);
        d = a.y - b.y; posAcc = fmaf(d, d, posAcc);
        d = a.z - b.z; posAcc = fmaf(d, d, posAcc);
        d = a.w - b.w; posAcc = fmaf(d, d, posAcc);
    }
    #pragma unroll
    for (int m = 16; m > 0; m >>= 1) posAcc += __shfl_xor(posAcc, m, 32);

    // ---------------- negative pairs: nontemporal loads --------------------
    float negAcc = 0.0f;
    #pragma unroll
    for (int t = 0; t < PPG; ++t) {
        const int i = __shfl(np.x, t, 32);
        const int j = __shfl(np.y, t, 32);
        const f4 a = __builtin_nontemporal_load(&Xv[i * D4 + lane]);
        const f4 b = __builtin_nontemporal_load(&Xv[j * D4 + lane]);
        float d, s = 0.0f;
        d = a[0] - b[0]; s = fmaf(d, d, s);
        d = a[1] - b[1]; s = fmaf(d, d, s);
        d = a[2] - b[2]; s = fmaf(d, d, s);
        d = a[3] - b[3]; s = fmaf(d, d, s);
        #pragma unroll
        for (int m = 16; m > 0; m >>= 1) s += __shfl_xor(s, m, 32);
        const float r = fmaxf(bias - sqrtf(s), 0.0f);
        negAcc = fmaf(r, r, negAcc);
    }
    // negAcc is group-uniform after the butterflies.

    __shared__ float sp[GPB], sn[GPB];
    if (lane == 0) { sp[group] = posAcc; sn[group] = negAcc; }
    __syncthreads();
    if (threadIdx.x == 0) {
        float P = 0.f, Nn = 0.f;
        #pragma unroll
        for (int g = 0; g < GPB; ++g) { P += sp[g]; Nn += sn[g]; }
        partials[2 * blockIdx.x]     = P;
        partials[2 * blockIdx.x + 1] = Nn;
    }
}

__global__ __launch_bounds__(TPB) void finalize_kernel(
    const float* __restrict__ partials, float* __restrict__ out)
{
    __shared__ float sp[TPB], sn[TPB];
    float p = 0.0f, n = 0.0f;
    for (int b = threadIdx.x; b < NBLK; b += TPB) {
        p += partials[2 * b];
        n += partials[2 * b + 1];
    }
    sp[threadIdx.x] = p; sn[threadIdx.x] = n;
    __syncthreads();
    for (int s = TPB / 2; s > 0; s >>= 1) {
        if ((int)threadIdx.x < s) {
            sp[threadIdx.x] += sp[threadIdx.x + s];
            sn[threadIdx.x] += sn[threadIdx.x + s];
        }
        __syncthreads();
    }
    if (threadIdx.x == 0) {
        out[0] = 0.5f * sp[0] / (float)NPAIRS;
        out[1] = 0.5f * sn[0] / (float)NPAIRS;
    }
}

extern "C" void kernel_launch(void* const* d_in, const int* in_sizes, int n_in,
                              void* d_out, int out_size, void* d_ws, size_t ws_size,
                              hipStream_t stream) {
    const float* X      = (const float*)d_in[0];
    // d_in[1] = scores (unused), d_in[3] = labels (unused)
    const float* h_bias = (const float*)d_in[2];
    const int2*  pos_p  = (const int2*)d_in[4];
    const int2*  neg_p  = (const int2*)d_in[5];
    float*       out    = (float*)d_out;
    float*       partials = (float*)d_ws;   // 2048*2 floats, fully written by pair_kernel

    pair_kernel<<<NBLK, TPB, 0, stream>>>(X, pos_p, neg_p, h_bias, partials);
    finalize_kernel<<<1, TPB, 0, stream>>>(partials, out);
}

// Round 11
// 90.388 us; speedup vs baseline: 1.8387x; 1.8387x over previous
//
#include <hip/hip_runtime.h>
#include <math.h>

#define NPAIRS  262144
#define D4      32                  // 128 floats = 32 float4 per row
#define TPB     256
#define NBLK    2048
#define GPB     (TPB / 32)          // 8 groups per block
#define NGROUPS (NBLK * GPB)        // 16384
#define PPG     (NPAIRS / NGROUPS)  // 16 pairs per group per list

// 32-lane group per pair; lane l holds float4 #l of each row (512B coalesced).
//
// FINAL (R11): exact revert to the R2 kernel -- the measured optimum (87.2us).
// Ten-round evidence for why this is the floor:
//  - fill (harness re-poison, 256MB @ 82% HBM peak): 41us, untouchable.
//  - pair kernel ~40us = L1 miss-path floor: 537MB of random 512B rows
//    (4.2M line fills). Insensitive to occupancy (R2), MLP batching (R4),
//    shfl count (R1). nt-loads bypass L2 not just L1 (R10: FETCH +43MB,
//    +20us). Conditional a-row register caching scratches (R8, R10: VGPR 40,
//    150MB spill WRITE traffic). Closed-form pos (R5-R9, 5 variants): setup
//    cost exceeded the ~20% of line fills pos contributes (pos b-rows L1-hit;
//    neg dominates misses).
//  - finalize + 2 launch gaps: ~6us.
//
// Reduction: per-block partials to d_ws + finalize kernel. Prev-session
// lesson: 2048-block atomicAdd to the SAME two addresses serializes at the
// TCC (~25us tail) -- never again.
__global__ __launch_bounds__(TPB, 6) void pair_kernel(
    const float* __restrict__ X,
    const int2*  __restrict__ pos_p,   // pos_idx as int2 stream
    const int2*  __restrict__ neg_p,   // neg_idx as int2 stream
    const float* __restrict__ h_bias,
    float* __restrict__ partials)
{
    const int lane  = threadIdx.x & 31;
    const int group = threadIdx.x >> 5;
    const int gid   = (blockIdx.x * TPB + threadIdx.x) >> 5;

    const float4* __restrict__ X4 = (const float4*)X;

    // numerically stable softplus(h_bias)
    const float hb   = h_bias[0];
    const float bias = fmaxf(hb, 0.0f) + log1pf(expf(-fabsf(hb)));

    // Preload this group's 16 pairs from each list (lanes 16..31 duplicate
    // lanes 0..15 -- same cacheline; shfl broadcasts read lanes 0..15).
    const int2 pp = pos_p[gid * PPG + (lane & (PPG - 1))];
    const int2 np = neg_p[gid * PPG + (lane & (PPG - 1))];

    // ---------------- positive pairs: separable, no per-pair reduce --------
    float posAcc = 0.0f;
    #pragma unroll
    for (int t = 0; t < PPG; ++t) {
        const int i = __shfl(pp.x, t, 32);
        const int j = __shfl(pp.y, t, 32);
        const float4 a = X4[i * D4 + lane];
        const float4 b = X4[j * D4 + lane];
        float d;
        d = a.x - b.x; posAcc = fmaf(d, d, posAcc);
        d = a.y - b.y; posAcc = fmaf(d, d, posAcc);
        d = a.z - b.z; posAcc = fmaf(d, d, posAcc);
        d = a.w - b.w; posAcc = fmaf(d, d, posAcc);
    }
    #pragma unroll
    for (int m = 16; m > 0; m >>= 1) posAcc += __shfl_xor(posAcc, m, 32);

    // ---------------- negative pairs: per-pair butterfly + margin ----------
    float negAcc = 0.0f;
    #pragma unroll
    for (int t = 0; t < PPG; ++t) {
        const int i = __shfl(np.x, t, 32);
        const int j = __shfl(np.y, t, 32);
        const float4 a = X4[i * D4 + lane];
        const float4 b = X4[j * D4 + lane];
        float d, s = 0.0f;
        d = a.x - b.x; s = fmaf(d, d, s);
        d = a.y - b.y; s = fmaf(d, d, s);
        d = a.z - b.z; s = fmaf(d, d, s);
        d = a.w - b.w; s = fmaf(d, d, s);
        #pragma unroll
        for (int m = 16; m > 0; m >>= 1) s += __shfl_xor(s, m, 32);
        const float r = fmaxf(bias - sqrtf(s), 0.0f);
        negAcc = fmaf(r, r, negAcc);
    }
    // negAcc is group-uniform after the butterflies.

    __shared__ float sp[GPB], sn[GPB];
    if (lane == 0) { sp[group] = posAcc; sn[group] = negAcc; }
    __syncthreads();
    if (threadIdx.x == 0) {
        float P = 0.f, Nn = 0.f;
        #pragma unroll
        for (int g = 0; g < GPB; ++g) { P += sp[g]; Nn += sn[g]; }
        partials[2 * blockIdx.x]     = P;
        partials[2 * blockIdx.x + 1] = Nn;
    }
}

__global__ __launch_bounds__(TPB) void finalize_kernel(
    const float* __restrict__ partials, float* __restrict__ out)
{
    __shared__ float sp[TPB], sn[TPB];
    float p = 0.0f, n = 0.0f;
    for (int b = threadIdx.x; b < NBLK; b += TPB) {
        p += partials[2 * b];
        n += partials[2 * b + 1];
    }
    sp[threadIdx.x] = p; sn[threadIdx.x] = n;
    __syncthreads();
    for (int s = TPB / 2; s > 0; s >>= 1) {
        if ((int)threadIdx.x < s) {
            sp[threadIdx.x] += sp[threadIdx.x + s];
            sn[threadIdx.x] += sn[threadIdx.x + s];
        }
        __syncthreads();
    }
    if (threadIdx.x == 0) {
        out[0] = 0.5f * sp[0] / (float)NPAIRS;
        out[1] = 0.5f * sn[0] / (float)NPAIRS;
    }
}

extern "C" void kernel_launch(void* const* d_in, const int* in_sizes, int n_in,
                              void* d_out, int out_size, void* d_ws, size_t ws_size,
                              hipStream_t stream) {
    const float* X      = (const float*)d_in[0];
    // d_in[1] = scores (unused), d_in[3] = labels (unused)
    const float* h_bias = (const float*)d_in[2];
    const int2*  pos_p  = (const int2*)d_in[4];
    const int2*  neg_p  = (const int2*)d_in[5];
    float*       out    = (float*)d_out;
    float*       partials = (float*)d_ws;   // 2048*2 floats, fully written by pair_kernel

    pair_kernel<<<NBLK, TPB, 0, stream>>>(X, pos_p, neg_p, h_bias, partials);
    finalize_kernel<<<1, TPB, 0, stream>>>(partials, out);
}